// Round 3
// baseline (2705.857 us; speedup 1.0000x reference)
//
#include <hip/hip_runtime.h>
#include <cstdint>
#include <cstddef>

typedef unsigned short u16;
typedef __bf16 bf16x8 __attribute__((ext_vector_type(8)));
typedef unsigned short u16x8 __attribute__((ext_vector_type(8)));
typedef float f32x4 __attribute__((ext_vector_type(4)));

#define TDIM 4096
#define HDIM 1024
#define FDIM 3584
#define NEXP 8

__device__ __forceinline__ u16 f2b(float f) {
  unsigned u = __float_as_uint(f);
  u += 0x7fff + ((u >> 16) & 1);   // round-to-nearest-even
  return (u16)(u >> 16);
}

// ---------------------------------------------------------------- router ----
// One wave per token, all fp32: logits = x @ gate_w, softmax -> top2 ->
// renormalize. Exact fp32 selection (matches the fp32 reference's top_k).
__global__ __launch_bounds__(256) void router_kernel(
    const float* __restrict__ X,       // [T][H]
    const float* __restrict__ GW,      // [H][E]
    float* __restrict__ combine,       // [T][E]
    float* __restrict__ logits_out) {  // [T][E]
  const int wave = threadIdx.x >> 6;
  const int lane = threadIdx.x & 63;
  const int t = blockIdx.x * 4 + wave;
  const float* xt = X + (size_t)t * HDIM;

  float acc[NEXP];
#pragma unroll
  for (int e = 0; e < NEXP; ++e) acc[e] = 0.f;

  const int h0 = lane * 16;  // 64 lanes * 16 = 1024 = H
#pragma unroll
  for (int jj = 0; jj < 4; ++jj) {
    const float4 xv = *(const float4*)(xt + h0 + jj * 4);
    const float xs[4] = {xv.x, xv.y, xv.z, xv.w};
#pragma unroll
    for (int r = 0; r < 4; ++r) {
      const int h = h0 + jj * 4 + r;
      const float4 g0 = *(const float4*)(GW + (size_t)h * NEXP);
      const float4 g1 = *(const float4*)(GW + (size_t)h * NEXP + 4);
      acc[0] += xs[r] * g0.x; acc[1] += xs[r] * g0.y;
      acc[2] += xs[r] * g0.z; acc[3] += xs[r] * g0.w;
      acc[4] += xs[r] * g1.x; acc[5] += xs[r] * g1.y;
      acc[6] += xs[r] * g1.z; acc[7] += xs[r] * g1.w;
    }
  }
#pragma unroll
  for (int off = 32; off > 0; off >>= 1) {
#pragma unroll
    for (int e = 0; e < NEXP; ++e) acc[e] += __shfl_xor(acc[e], off, 64);
  }
  if (lane == 0) {
    int i1 = 0;
#pragma unroll
    for (int e = 1; e < NEXP; ++e) if (acc[e] > acc[i1]) i1 = e;
    int i2 = (i1 == 0) ? 1 : 0;
#pragma unroll
    for (int e = 0; e < NEXP; ++e) if (e != i2 && e != i1 && acc[e] > acc[i2]) i2 = e;
    const float w2 = __expf(acc[i2] - acc[i1]);
    const float s = 1.f + w2;
    const float wA = 1.f / s;
    const float wB = w2 / s;
#pragma unroll
    for (int e = 0; e < NEXP; ++e) {
      combine[(size_t)t * NEXP + e] = (e == i1) ? wA : ((e == i2) ? wB : 0.f);
      logits_out[(size_t)t * NEXP + e] = acc[e];
    }
  }
}

// ---------------------------------------------------------------- GEMM 1 ----
// inner = silu(X @ Wu) * (X @ Wg). X fp32 [chunk][H]; Wu/Wg fp32 [H][F]
// (k-major) -> fp32 loads, cvt to bf16 in regs, LDS stores (B transposed).
// Tile BM=128, BN=64, BK=32; 4 waves, each 64x32 (4x2 16x16x32 frags).
__global__ __launch_bounds__(256) void gemm1_kernel(
    const float* __restrict__ X,
    const float* __restrict__ Wu,
    const float* __restrict__ Wg,
    u16* __restrict__ inner) {   // bf16 [chunk][F]
  __shared__ __align__(16) u16 As[128 * 40];
  __shared__ __align__(16) u16 BuS[64 * 40];
  __shared__ __align__(16) u16 BgS[64 * 40];
  const int m0 = blockIdx.y * 128;
  const int n0 = blockIdx.x * 64;
  const int tid = threadIdx.x;
  const int wave = tid >> 6, lane = tid & 63;
  const int wm = (wave >> 1) * 64, wn = (wave & 1) * 32;
  const int l15 = lane & 15;
  const int quad = lane >> 4;
  const int kq = quad * 8;

  f32x4 au[4][2], ag[4][2];
  const f32x4 fzero = {0.f, 0.f, 0.f, 0.f};
#pragma unroll
  for (int i = 0; i < 4; ++i)
#pragma unroll
    for (int j = 0; j < 2; ++j) { au[i][j] = fzero; ag[i][j] = fzero; }

  const int ar = tid >> 2;         // 0..63   (A staging row)
  const int ac = (tid & 3) << 3;   // 0,8,16,24 (A staging k-col)
  const int kr = tid >> 3;         // 0..31   (B staging k-row)
  const int j8 = (tid & 7) << 3;   // 0..56   (B staging n-base)

  for (int k0 = 0; k0 < HDIM; k0 += 32) {
#pragma unroll
    for (int h = 0; h < 2; ++h) {
      const float* src = X + (size_t)(m0 + ar + 64 * h) * HDIM + k0 + ac;
      const float4 v0 = *(const float4*)(src);
      const float4 v1 = *(const float4*)(src + 4);
      u16x8 o;
      o[0] = f2b(v0.x); o[1] = f2b(v0.y); o[2] = f2b(v0.z); o[3] = f2b(v0.w);
      o[4] = f2b(v1.x); o[5] = f2b(v1.y); o[6] = f2b(v1.z); o[7] = f2b(v1.w);
      *(u16x8*)(As + (ar + 64 * h) * 40 + ac) = o;
    }
    {
      const float* bu = Wu + (size_t)(k0 + kr) * FDIM + n0 + j8;
      const float4 b0 = *(const float4*)(bu);
      const float4 b1 = *(const float4*)(bu + 4);
      BuS[(j8 + 0) * 40 + kr] = f2b(b0.x); BuS[(j8 + 1) * 40 + kr] = f2b(b0.y);
      BuS[(j8 + 2) * 40 + kr] = f2b(b0.z); BuS[(j8 + 3) * 40 + kr] = f2b(b0.w);
      BuS[(j8 + 4) * 40 + kr] = f2b(b1.x); BuS[(j8 + 5) * 40 + kr] = f2b(b1.y);
      BuS[(j8 + 6) * 40 + kr] = f2b(b1.z); BuS[(j8 + 7) * 40 + kr] = f2b(b1.w);
      const float* bg = Wg + (size_t)(k0 + kr) * FDIM + n0 + j8;
      const float4 c0 = *(const float4*)(bg);
      const float4 c1 = *(const float4*)(bg + 4);
      BgS[(j8 + 0) * 40 + kr] = f2b(c0.x); BgS[(j8 + 1) * 40 + kr] = f2b(c0.y);
      BgS[(j8 + 2) * 40 + kr] = f2b(c0.z); BgS[(j8 + 3) * 40 + kr] = f2b(c0.w);
      BgS[(j8 + 4) * 40 + kr] = f2b(c1.x); BgS[(j8 + 5) * 40 + kr] = f2b(c1.y);
      BgS[(j8 + 6) * 40 + kr] = f2b(c1.z); BgS[(j8 + 7) * 40 + kr] = f2b(c1.w);
    }
    __syncthreads();

    bf16x8 af[4], buf[2], bgf[2];
#pragma unroll
    for (int mi = 0; mi < 4; ++mi)
      af[mi] = *(const bf16x8*)(As + (wm + mi * 16 + l15) * 40 + kq);
#pragma unroll
    for (int ni = 0; ni < 2; ++ni) {
      buf[ni] = *(const bf16x8*)(BuS + (wn + ni * 16 + l15) * 40 + kq);
      bgf[ni] = *(const bf16x8*)(BgS + (wn + ni * 16 + l15) * 40 + kq);
    }
#pragma unroll
    for (int mi = 0; mi < 4; ++mi)
#pragma unroll
      for (int ni = 0; ni < 2; ++ni) {
        au[mi][ni] = __builtin_amdgcn_mfma_f32_16x16x32_bf16(af[mi], buf[ni], au[mi][ni], 0, 0, 0);
        ag[mi][ni] = __builtin_amdgcn_mfma_f32_16x16x32_bf16(af[mi], bgf[ni], ag[mi][ni], 0, 0, 0);
      }
    __syncthreads();
  }
#pragma unroll
  for (int mi = 0; mi < 4; ++mi)
#pragma unroll
    for (int ni = 0; ni < 2; ++ni)
#pragma unroll
      for (int r = 0; r < 4; ++r) {
        const int row = m0 + wm + mi * 16 + quad * 4 + r;
        const int col = n0 + wn + ni * 16 + l15;
        const float u = au[mi][ni][r];
        const float g = ag[mi][ni][r];
        const float sv = u / (1.f + __expf(-u));
        inner[(size_t)row * FDIM + col] = f2b(sv * g);
      }
}

// ---------------------------------------------------------------- GEMM 2 ----
// out += combine[:,e] * (inner @ Wd). inner bf16 [chunk][F]; Wd fp32 [F][H]
// (k-major, cvt+transpose in staging). out fp32 RMW (zeroed at launch start).
__global__ __launch_bounds__(256) void gemm2_kernel(
    const u16* __restrict__ A,          // inner bf16 [chunk][F]
    const float* __restrict__ Wd,       // [F][H] fp32
    const float* __restrict__ combine,  // [chunk][E]
    float* __restrict__ outY,           // [chunk][H] fp32 accum
    int e) {
  __shared__ __align__(16) u16 As[128 * 40];
  __shared__ __align__(16) u16 Bs[64 * 40];
  const int m0 = blockIdx.y * 128;
  const int n0 = blockIdx.x * 64;
  const int tid = threadIdx.x;
  const int wave = tid >> 6, lane = tid & 63;
  const int wm = (wave >> 1) * 64, wn = (wave & 1) * 32;
  const int l15 = lane & 15;
  const int quad = lane >> 4;
  const int kq = quad * 8;

  f32x4 acc[4][2];
  const f32x4 fzero = {0.f, 0.f, 0.f, 0.f};
#pragma unroll
  for (int i = 0; i < 4; ++i)
#pragma unroll
    for (int j = 0; j < 2; ++j) acc[i][j] = fzero;

  const int ar = tid >> 2;
  const int ac = (tid & 3) << 3;
  const int kr = tid >> 3;
  const int j8 = (tid & 7) << 3;

  for (int k0 = 0; k0 < FDIM; k0 += 32) {
    *(u16x8*)(As + ar * 40 + ac) =
        *(const u16x8*)(A + (size_t)(m0 + ar) * FDIM + k0 + ac);
    *(u16x8*)(As + (ar + 64) * 40 + ac) =
        *(const u16x8*)(A + (size_t)(m0 + ar + 64) * FDIM + k0 + ac);
    {
      const float* bd = Wd + (size_t)(k0 + kr) * HDIM + n0 + j8;
      const float4 b0 = *(const float4*)(bd);
      const float4 b1 = *(const float4*)(bd + 4);
      Bs[(j8 + 0) * 40 + kr] = f2b(b0.x); Bs[(j8 + 1) * 40 + kr] = f2b(b0.y);
      Bs[(j8 + 2) * 40 + kr] = f2b(b0.z); Bs[(j8 + 3) * 40 + kr] = f2b(b0.w);
      Bs[(j8 + 4) * 40 + kr] = f2b(b1.x); Bs[(j8 + 5) * 40 + kr] = f2b(b1.y);
      Bs[(j8 + 6) * 40 + kr] = f2b(b1.z); Bs[(j8 + 7) * 40 + kr] = f2b(b1.w);
    }
    __syncthreads();

    bf16x8 af[4], bf[2];
#pragma unroll
    for (int mi = 0; mi < 4; ++mi)
      af[mi] = *(const bf16x8*)(As + (wm + mi * 16 + l15) * 40 + kq);
#pragma unroll
    for (int ni = 0; ni < 2; ++ni)
      bf[ni] = *(const bf16x8*)(Bs + (wn + ni * 16 + l15) * 40 + kq);
#pragma unroll
    for (int mi = 0; mi < 4; ++mi)
#pragma unroll
      for (int ni = 0; ni < 2; ++ni)
        acc[mi][ni] = __builtin_amdgcn_mfma_f32_16x16x32_bf16(af[mi], bf[ni], acc[mi][ni], 0, 0, 0);
    __syncthreads();
  }
#pragma unroll
  for (int mi = 0; mi < 4; ++mi)
#pragma unroll
    for (int ni = 0; ni < 2; ++ni)
#pragma unroll
      for (int r = 0; r < 4; ++r) {
        const int row = m0 + wm + mi * 16 + quad * 4 + r;
        const int col = n0 + wn + ni * 16 + l15;
        const float w = combine[(size_t)row * NEXP + e];
        outY[(size_t)row * HDIM + col] += w * acc[mi][ni][r];
      }
}

// ----------------------------------------------------------------- launch ---
extern "C" void kernel_launch(void* const* d_in, const int* in_sizes, int n_in,
                              void* d_out, int out_size, void* d_ws, size_t ws_size,
                              hipStream_t stream) {
  const float* x      = (const float*)d_in[0];  // [T][H] fp32
  const float* gate_w = (const float*)d_in[1];  // [H][E] fp32
  const float* w_up   = (const float*)d_in[2];  // [E][H][F] fp32
  const float* w_gate = (const float*)d_in[3];  // [E][H][F] fp32
  const float* w_down = (const float*)d_in[4];  // [E][F][H] fp32
  float* out = (float*)d_out;                   // y [T][H] fp32, then logits [T][E] fp32
  char* ws = (char*)d_ws;

  // ws layout: combine fp32 [T][8] @ 0 (131,072 B); inner bf16 [chunk][F]
  // after it. chunk picked to fit ws_size (harness re-poisons ws each call,
  // so everything we read from ws must be written first within this launch).
  float* combine = (float*)ws;
  u16* inner = (u16*)(ws + 131072);

  int chunk = 128;
  const int cand[6] = {4096, 2048, 1024, 512, 256, 128};
  for (int i = 0; i < 6; ++i) {
    if (131072u + (size_t)cand[i] * FDIM * 2 <= ws_size) { chunk = cand[i]; break; }
  }

  // zero y region (harness poisons d_out with 0xAA before timed replays)
  hipMemsetAsync(out, 0, (size_t)TDIM * HDIM * sizeof(float), stream);

  router_kernel<<<TDIM / 4, 256, 0, stream>>>(x, gate_w, combine,
                                              out + (size_t)TDIM * HDIM);

  for (int e = 0; e < NEXP; ++e) {
    const size_t wofs  = (size_t)e * HDIM * FDIM;  // up/gate expert stride
    const size_t wofsd = (size_t)e * FDIM * HDIM;  // down expert stride
    for (int c = 0; c < TDIM / chunk; ++c) {
      const size_t tofs = (size_t)c * chunk;
      gemm1_kernel<<<dim3(FDIM / 64, chunk / 128), 256, 0, stream>>>(
          x + tofs * HDIM, w_up + wofs, w_gate + wofs, inner);
      gemm2_kernel<<<dim3(HDIM / 64, chunk / 128), 256, 0, stream>>>(
          inner, w_down + wofsd, combine + tofs * NEXP, out + tofs * HDIM, e);
    }
  }
}